// Round 5
// baseline (347.464 us; speedup 1.0000x reference)
//
#include <hip/hip_runtime.h>

typedef __attribute__((ext_vector_type(8))) short short8v;
typedef __attribute__((ext_vector_type(4))) float f32x4;

// ws layout:
//   ushort [0 .. 327679]  : W bf16 panels [part(2)][gate(80)][k(2048)]
//   float  [163840 ..]    : constants
#define WSL   163840           // loss column (80 f32)
#define WSC1  (WSL+80)         // folded gate-1 constants (80)
#define WSC2  (WSC1+80)        // folded gate-2 constants (80)
#define WSPF  (WSC2+80)        // poly factor scalar

__device__ __forceinline__ float fsig(float x){ return 1.0f/(1.0f + __expf(-x)); }
__device__ __forceinline__ float ftanh(float x){ float e = __expf(2.0f*x); return 1.0f - 2.0f/(e+1.0f); }
__device__ __forceinline__ unsigned short f2bf_rne(float f){
  unsigned u = __float_as_uint(f);
  u += 0x7fffu + ((u >> 16) & 1u);
  return (unsigned short)(u >> 16);
}
// pack two floats -> two bf16 (round-half-up; error negligible here, validated R4)
__device__ __forceinline__ unsigned pack2bf(float lo, float hi){
  unsigned a = __float_as_uint(lo) + 0x8000u;
  unsigned b = __float_as_uint(hi) + 0x8000u;
  return (a >> 16) | (b & 0xFFFF0000u);
}

__global__ __launch_bounds__(256,1) void prep_kernel(
    const float* __restrict__ W_ih1, const float* __restrict__ b_ih1,
    const float* __restrict__ W_hh1, const float* __restrict__ b_hh1,
    const float* __restrict__ b_ih2, const float* __restrict__ W_hh2,
    const float* __restrict__ b_hh2, const float* __restrict__ h1_0,
    const float* __restrict__ h2_0, const float* __restrict__ alpha_raw,
    const int* __restrict__ t, float* __restrict__ ws)
{
  const int b = blockIdx.x;            // 160 blocks: gate(80) x part(2)
  const int gate = b >> 1, part = b & 1;
  const float* src = W_ih1 + (size_t)gate*4097 + (part ? 2049 : 0);
  unsigned short* dst = (unsigned short*)ws + (size_t)part*163840 + (size_t)gate*2048;
  for (int k = threadIdx.x; k < 2048; k += 256) dst[k] = f2bf_rne(src[k]);
  if (b == 0) {
    const int tix = threadIdx.x;
    if (tix < 80) {
      float s = b_ih1[tix] + b_hh1[tix];
      for (int j = 0; j < 20; ++j) s += W_hh1[tix*20+j]*h1_0[j];
      ws[WSC1+tix] = s;
    } else if (tix < 160) {
      const int kk = tix - 80;
      float s = b_ih2[kk] + b_hh2[kk];
      for (int j = 0; j < 20; ++j) s += W_hh2[kk*20+j]*h2_0[j];
      ws[WSC2+kk] = s;
    } else if (tix < 240) {
      const int kk = tix - 160;
      ws[WSL+kk] = W_ih1[(size_t)kk*4097 + 2048];   // loss column
    } else if (tix == 240) {
      const float tv = (float)(*t);
      float pf = 0.f, term = 1.f;
      for (int j = 0; j < 3; ++j) {
        float a = alpha_raw[j];
        float sp = (a > 20.f) ? a : log1pf(__expf(a));
        pf += sp*term; term *= tv;                   // t^0 == 1 even at t=0
      }
      pf *= powf(0.99f, tv);
      ws[WSPF] = pf;
    }
  }
}

// 256 blocks x 512 thr. Block = 16 rows. 8 waves = part(2) x k-slice(4 x 512).
// MFMA 16x16x32 bf16; per wave 5 N-tiles (80 gates of its part).
// x/grad: non-temporal (read-once; keeps W panel L2-resident).
// unroll 1 + 1-deep A prefetch: peak live VGPR ~70 -> no spills under 128 cap.
__global__ __launch_bounds__(512,2) void main_kernel(
    const float* __restrict__ x, const float* __restrict__ loss,
    const float* __restrict__ grad, const float* __restrict__ W_ih2,
    const float* __restrict__ W_out, const float* __restrict__ b_out,
    const float* __restrict__ c1_0, const float* __restrict__ c2_0,
    const float* __restrict__ ws, float* __restrict__ out)
{
  __shared__ float pbuf[2][16][168];   // f32 gate partials, atomicAdd combine
  __shared__ float wih2[1600];
  __shared__ float g1[16][80];
  __shared__ float h1s[16][20], h2s[16][20];
  __shared__ float c10[20], c20[20];
  __shared__ float invX[16], invG[16], lscA[16], axv[16];
  __shared__ unsigned smaxX[16], smaxG[16];

  const int tid  = threadIdx.x;
  const int w    = tid >> 6, lane = tid & 63;
  const int part = w >> 2, wk = w & 3;
  const int m    = lane & 15, kg = lane >> 4;
  const int r0   = blockIdx.x * 16;

  for (int i = tid; i < 2*16*168; i += 512) (&pbuf[0][0][0])[i] = 0.f;
  for (int i = tid; i < 1600; i += 512) wih2[i] = W_ih2[i];
  if (tid < 20) { c10[tid] = c1_0[tid]; c20[tid] = c2_0[tid]; }
  if (tid < 16) { smaxX[tid] = 0u; smaxG[tid] = 0u; }
  __syncthreads();

  const float* Ap = (part ? grad : x) + (size_t)(r0 + m)*2048 + wk*512 + kg*8;
  const unsigned short* Bp = (const unsigned short*)ws + (size_t)part*163840
                           + (size_t)m*2048 + wk*512 + kg*8;

  f32x4 acc[5];
  #pragma unroll
  for (int t = 0; t < 5; ++t) acc[t] = (f32x4){0.f,0.f,0.f,0.f};
  float vm = 0.f;

  f32x4 a0 = __builtin_nontemporal_load((const f32x4*)Ap);
  f32x4 a1 = __builtin_nontemporal_load((const f32x4*)(Ap + 4));
  #pragma unroll 1
  for (int ks = 0; ks < 16; ++ks) {
    const float* pn = Ap + ((ks < 15) ? (ks + 1) * 32 : 0);
    const f32x4 n0 = __builtin_nontemporal_load((const f32x4*)pn);
    const f32x4 n1 = __builtin_nontemporal_load((const f32x4*)(pn + 4));
    vm = fmaxf(vm, fmaxf(fmaxf(fabsf(a0.x),fabsf(a0.y)), fmaxf(fabsf(a0.z),fabsf(a0.w))));
    vm = fmaxf(vm, fmaxf(fmaxf(fabsf(a1.x),fabsf(a1.y)), fmaxf(fabsf(a1.z),fabsf(a1.w))));
    union { unsigned u[4]; short8v v; } A_;
    A_.u[0] = pack2bf(a0.x, a0.y);
    A_.u[1] = pack2bf(a0.z, a0.w);
    A_.u[2] = pack2bf(a1.x, a1.y);
    A_.u[3] = pack2bf(a1.z, a1.w);
    const short8v af = A_.v;
    const unsigned short* bp = Bp + ks*32;
    #pragma unroll
    for (int t = 0; t < 5; ++t) {
      const short8v bf = *(const short8v*)(bp + (size_t)t*32768);
      acc[t] = __builtin_amdgcn_mfma_f32_16x16x32_bf16(af, bf, acc[t], 0, 0, 0);
    }
    a0 = n0; a1 = n1;
  }

  // row-max reduce across the 4 k-groups holding the same row (xor 16, 32)
  vm = fmaxf(vm, __shfl_xor(vm, 16));
  vm = fmaxf(vm, __shfl_xor(vm, 32));
  if (lane < 16) atomicMax(part ? &smaxG[m] : &smaxX[m], __float_as_uint(vm));

  #pragma unroll
  for (int t = 0; t < 5; ++t)
    #pragma unroll
    for (int r = 0; r < 4; ++r)
      atomicAdd(&pbuf[part][kg*4 + r][t*16 + m], acc[t][r]);
  __syncthreads();

  if (tid < 16) {
    float ax = __uint_as_float(smaxX[tid]); ax = (ax > 0.f) ? ax : 1.0f;
    axv[tid] = ax; invX[tid] = 1.0f/ax;
    float ag = __uint_as_float(smaxG[tid]); ag = (ag > 0.f) ? ag : 1.0f;
    invG[tid] = 1.0f/ag;
    float l  = loss[r0 + tid];
    float al = fabsf(l); al = (al > 0.f) ? al : 1.0f;
    lscA[tid] = l / al;
  }
  __syncthreads();

  for (int idx = tid; idx < 1280; idx += 512) {      // gates 1 (16 rows x 80)
    const int r = idx / 80, k2 = idx - r*80;
    g1[r][k2] = pbuf[0][r][k2]*invX[r] + pbuf[1][r][k2]*invG[r]
              + ws[WSL+k2]*lscA[r] + ws[WSC1+k2];
  }
  __syncthreads();

  if (tid < 320) {                                   // cell 1 (16 rows x 20)
    const int r = tid / 20, j = tid - r*20;
    const float gi = g1[r][j], gf = g1[r][20+j], gc = g1[r][40+j], go = g1[r][60+j];
    const float c1 = fsig(gf)*c10[j] + fsig(gi)*ftanh(gc);
    h1s[r][j] = fsig(go)*ftanh(c1);
  }
  __syncthreads();

  for (int idx = tid; idx < 1280; idx += 512) {      // gates 2
    const int r = idx / 80, k2 = idx - r*80;
    float s = ws[WSC2+k2];
    #pragma unroll
    for (int j = 0; j < 20; ++j) s += wih2[k2*20+j]*h1s[r][j];
    g1[r][k2] = s;
  }
  __syncthreads();

  if (tid < 320) {                                   // cell 2
    const int r = tid / 20, j = tid - r*20;
    const float gi = g1[r][j], gf = g1[r][20+j], gc = g1[r][40+j], go = g1[r][60+j];
    const float c2v = fsig(gf)*c20[j] + fsig(gi)*ftanh(gc);
    h2s[r][j] = fsig(go)*ftanh(c2v);
  }
  __syncthreads();

  const float pf = ws[WSPF];                         // output GEMV + tanh + scale
  #pragma unroll
  for (int q = 0; q < 4; ++q) {
    const int d = q*512 + tid;
    const float4* wr = (const float4*)(W_out + (size_t)d*20);
    const float4 w0 = wr[0], w1 = wr[1], w2 = wr[2], w3 = wr[3], w4 = wr[4];
    const float bo = b_out[d];
    #pragma unroll
    for (int r = 0; r < 16; ++r) {
      const float4* hp = (const float4*)&h2s[r][0];
      const float4 h0 = hp[0], h1v = hp[1], h2v = hp[2], h3v = hp[3], h4v = hp[4];
      float v = bo;
      v += w0.x*h0.x  + w0.y*h0.y  + w0.z*h0.z  + w0.w*h0.w;
      v += w1.x*h1v.x + w1.y*h1v.y + w1.z*h1v.z + w1.w*h1v.w;
      v += w2.x*h2v.x + w2.y*h2v.y + w2.z*h2v.z + w2.w*h2v.w;
      v += w3.x*h3v.x + w3.y*h3v.y + w3.z*h3v.z + w3.w*h3v.w;
      v += w4.x*h4v.x + w4.y*h4v.y + w4.z*h4v.z + w4.w*h4v.w;
      __builtin_nontemporal_store(pf * axv[r] * ftanh(v),
                                  &out[(size_t)(r0+r)*2048 + d]);
    }
  }
}

extern "C" void kernel_launch(void* const* d_in, const int* in_sizes, int n_in,
                              void* d_out, int out_size, void* d_ws, size_t ws_size,
                              hipStream_t stream)
{
  const float* x      = (const float*)d_in[0];
  const float* loss   = (const float*)d_in[1];
  const float* grad   = (const float*)d_in[2];
  const float* W_ih1  = (const float*)d_in[3];
  const float* b_ih1  = (const float*)d_in[4];
  const float* W_hh1  = (const float*)d_in[5];
  const float* b_hh1  = (const float*)d_in[6];
  const float* W_ih2  = (const float*)d_in[7];
  const float* b_ih2  = (const float*)d_in[8];
  const float* W_hh2  = (const float*)d_in[9];
  const float* b_hh2  = (const float*)d_in[10];
  const float* W_out  = (const float*)d_in[11];
  const float* b_out  = (const float*)d_in[12];
  const float* h1_0   = (const float*)d_in[13];
  const float* c1_0   = (const float*)d_in[14];
  const float* h2_0   = (const float*)d_in[15];
  const float* c2_0   = (const float*)d_in[16];
  const float* alpha  = (const float*)d_in[17];
  const int*   t      = (const int*)d_in[18];
  float* ws  = (float*)d_ws;
  float* out = (float*)d_out;

  hipLaunchKernelGGL(prep_kernel, dim3(160), dim3(256), 0, stream,
                     W_ih1, b_ih1, W_hh1, b_hh1, b_ih2, W_hh2, b_hh2,
                     h1_0, h2_0, alpha, t, ws);
  hipLaunchKernelGGL(main_kernel, dim3(256), dim3(512), 0, stream,
                     x, loss, grad, W_ih2, W_out, b_out, c1_0, c2_0, ws, out);
}

// Round 7
// 208.452 us; speedup vs baseline: 1.6669x; 1.6669x over previous
//
#include <hip/hip_runtime.h>

typedef __attribute__((ext_vector_type(8))) short short8v;
typedef __attribute__((ext_vector_type(4))) float f32x4;

// ws layout (float offsets)
//  [0 .. 163839]   bf16 panel [gate(160)][k(2048)]  (ushort)
#define WSL   163840           // loss column (80)
#define WSC1  (WSL+80)         // folded gate-1 constants (80)
#define WSC2  (WSC1+80)        // folded gate-2 constants (80)
#define WSPF  (WSC2+80)        // poly factor
#define NORMX 164096           // 4096 row maxes of |x|   (f32 via uint atomicMax)
#define NORMG (NORMX+4096)     // 4096 row maxes of |grad|
#define PART  172288           // f32 partials [NS][4096][160]

__device__ __forceinline__ float fsig(float x){ return 1.0f/(1.0f + __expf(-x)); }
__device__ __forceinline__ float ftanh(float x){ float e = __expf(2.0f*x); return 1.0f - 2.0f/(e+1.0f); }
__device__ __forceinline__ unsigned short f2bf_rne(float f){
  unsigned u = __float_as_uint(f);
  u += 0x7fffu + ((u >> 16) & 1u);
  return (unsigned short)(u >> 16);
}
__device__ __forceinline__ unsigned pack2bf(float lo, float hi){
  unsigned a = __float_as_uint(lo) + 0x8000u;
  unsigned b = __float_as_uint(hi) + 0x8000u;
  return (a >> 16) | (b & 0xFFFF0000u);
}

__global__ __launch_bounds__(256,1) void prep_kernel(
    const float* __restrict__ W_ih1, const float* __restrict__ b_ih1,
    const float* __restrict__ W_hh1, const float* __restrict__ b_hh1,
    const float* __restrict__ b_ih2, const float* __restrict__ W_hh2,
    const float* __restrict__ b_hh2, const float* __restrict__ h1_0,
    const float* __restrict__ h2_0, const float* __restrict__ alpha_raw,
    const int* __restrict__ t, float* __restrict__ ws)
{
  const int g = blockIdx.x;            // 160 gates: 0..79 x-part, 80..159 grad-part
  const int wr = (g < 80) ? g : g - 80;
  const float* src = W_ih1 + (size_t)wr*4097 + ((g < 80) ? 0 : 2049);
  unsigned short* dst = (unsigned short*)ws + (size_t)g*2048;
  for (int k = threadIdx.x; k < 2048; k += 256) dst[k] = f2bf_rne(src[k]);
  if (g == 0) {
    const int tix = threadIdx.x;
    if (tix < 80) {
      float s = b_ih1[tix] + b_hh1[tix];
      for (int j = 0; j < 20; ++j) s += W_hh1[tix*20+j]*h1_0[j];
      ws[WSC1+tix] = s;
    } else if (tix < 160) {
      const int kk = tix - 80;
      float s = b_ih2[kk] + b_hh2[kk];
      for (int j = 0; j < 20; ++j) s += W_hh2[kk*20+j]*h2_0[j];
      ws[WSC2+kk] = s;
    } else if (tix < 240) {
      const int kk = tix - 160;
      ws[WSL+kk] = W_ih1[(size_t)kk*4097 + 2048];   // loss column
    } else if (tix == 240) {
      const float tv = (float)(*t);
      float pf = 0.f, term = 1.f;
      for (int j = 0; j < 3; ++j) {
        float a = alpha_raw[j];
        float sp = (a > 20.f) ? a : log1pf(__expf(a));
        pf += sp*term; term *= tv;                   // t^0 == 1 even at t=0
      }
      pf *= powf(0.99f, tv);
      ws[WSPF] = pf;
    }
  }
}

// GEMM: grid = 64 rowblocks x NS kslices, 512 thr = 8 waves (4 m-tiles x 2 parts).
// B chunk (160 gates x 128 k bf16 = 40KB) staged in LDS, XOR-swizzled; all MFMA
// operands from LDS/registers. kslice == blockIdx%NS -> one kslice per XCD (NS=8).
template<int NS>
__global__ __launch_bounds__(512,2) void gemm_kernel(
    const float* __restrict__ x, const float* __restrict__ grad,
    const float* ws, float* wsw)
{
  constexpr int KS  = 2048 / NS;       // K per slice (per part)
  constexpr int NCH = KS / 128;        // 128-col chunks per slice
  __shared__ unsigned short bs[160*128];   // 40 KB

  const int tid = threadIdx.x;
  const int w = tid >> 6, lane = tid & 63;
  const int mt = w >> 1, gh = w & 1;   // m-tile 0..3, part: 0=x 1=grad
  const int m = lane & 15, kg = lane >> 4;
  const int rb  = blockIdx.x / NS, ksl = blockIdx.x % NS;
  const int r0  = rb*64;
  const int kbase = ksl*KS;
  const unsigned short* panel = (const unsigned short*)ws;
  const float* Ap = (gh ? grad : x) + (size_t)(r0 + mt*16 + m)*2048;
  const int xk = (m & 7) << 4;         // per-lane swizzle constant

  f32x4 acc[5];
  #pragma unroll
  for (int t = 0; t < 5; ++t) acc[t] = (f32x4){0.f,0.f,0.f,0.f};
  float vm = 0.f;

  #pragma unroll 1
  for (int c = 0; c < NCH; ++c) {
    const int kb = kbase + c*128;
    // ---- stage B chunk: 160 gates x 16 chunks of 16B, swizzled ----
    #pragma unroll
    for (int q = 0; q < 5; ++q) {
      const int j = q*512 + tid;       // 0..2559
      const int g = j >> 4, ku = j & 15;
      const uint4 v = *(const uint4*)(panel + (size_t)g*2048 + kb + ku*8);
      *(uint4*)((char*)bs + g*256 + ((ku*16) ^ ((g & 7) << 4))) = v;
    }
    __syncthreads();
    // ---- 4 k-steps x 5 MFMA ----
    #pragma unroll
    for (int ks = 0; ks < 4; ++ks) {
      const float* ap = Ap + kb + ks*32 + kg*8;
      const f32x4 a0 = *(const f32x4*)ap;
      const f32x4 a1 = *(const f32x4*)(ap + 4);
      vm = fmaxf(vm, fmaxf(fmaxf(fabsf(a0.x),fabsf(a0.y)), fmaxf(fabsf(a0.z),fabsf(a0.w))));
      vm = fmaxf(vm, fmaxf(fmaxf(fabsf(a1.x),fabsf(a1.y)), fmaxf(fabsf(a1.z),fabsf(a1.w))));
      union { unsigned u[4]; short8v v; } A_;
      A_.u[0] = pack2bf(a0.x, a0.y);
      A_.u[1] = pack2bf(a0.z, a0.w);
      A_.u[2] = pack2bf(a1.x, a1.y);
      A_.u[3] = pack2bf(a1.z, a1.w);
      const short8v af = A_.v;
      const int kof = (ks*64 + kg*16) ^ xk;
      #pragma unroll
      for (int t = 0; t < 5; ++t) {
        const int lg = gh*80 + t*16 + m;
        const short8v bf = *(const short8v*)((char*)bs + lg*256 + kof);
        acc[t] = __builtin_amdgcn_mfma_f32_16x16x32_bf16(af, bf, acc[t], 0, 0, 0);
      }
    }
    __syncthreads();
  }

  // ---- row inf-norm: reduce over kg lanes, one global atomicMax per row ----
  vm = fmaxf(vm, __shfl_xor(vm, 16));
  vm = fmaxf(vm, __shfl_xor(vm, 32));
  if (lane < 16)
    atomicMax((unsigned*)wsw + (gh ? NORMG : NORMX) + r0 + mt*16 + m,
              __float_as_uint(vm));

  // ---- per-slice partials (exclusive ownership, no atomics) ----
  float* pp = wsw + PART + ((size_t)ksl*4096 + r0 + mt*16 + kg*4)*160 + gh*80 + m;
  #pragma unroll
  for (int t = 0; t < 5; ++t)
    #pragma unroll
    for (int r = 0; r < 4; ++r)
      pp[(size_t)r*160 + t*16] = acc[t][r];
}

// tail: 512 blocks x 256 thr; 8 rows each: reduce NS slices -> gates -> cells -> output
template<int NS>
__global__ __launch_bounds__(256,4) void tail_kernel(
    const float* __restrict__ loss, const float* __restrict__ W_ih2,
    const float* __restrict__ W_out, const float* __restrict__ b_out,
    const float* __restrict__ c1_0, const float* __restrict__ c2_0,
    const float* ws, float* __restrict__ out)
{
  __shared__ float raw[8][160];
  __shared__ float g1[8][80];
  __shared__ float wih2s[1600];
  __shared__ float h1s[8][20], h2s[8][20];
  __shared__ float c10[20], c20[20];
  __shared__ float invX[8], invG[8], lscA[8], axv[8];

  const int tid = threadIdx.x;
  const int r0  = blockIdx.x * 8;

  for (int i = tid; i < 1600; i += 256) wih2s[i] = W_ih2[i];
  if (tid < 20) { c10[tid] = c1_0[tid]; c20[tid] = c2_0[tid]; }

  #pragma unroll
  for (int q = 0; q < 5; ++q) {                 // reduce partials (8x160)
    const int idx = q*256 + tid;
    const int r = idx / 160, gt = idx - r*160;
    float s = 0.f;
    #pragma unroll
    for (int sl = 0; sl < NS; ++sl)
      s += ws[PART + ((size_t)sl*4096 + r0 + r)*160 + gt];
    raw[r][gt] = s;
  }
  if (tid < 8) {
    float ax = ws[NORMX + r0 + tid]; ax = (ax > 0.f) ? ax : 1.0f;
    axv[tid] = ax; invX[tid] = 1.0f/ax;
    float ag = ws[NORMG + r0 + tid]; ag = (ag > 0.f) ? ag : 1.0f;
    invG[tid] = 1.0f/ag;
    float l  = loss[r0 + tid];
    float al = fabsf(l); al = (al > 0.f) ? al : 1.0f;
    lscA[tid] = l / al;
  }
  __syncthreads();

  for (int q = 0; q < 3; ++q) {                 // gates 1 (8x80)
    const int idx = q*256 + tid;
    if (idx < 640) {
      const int r = idx / 80, k2 = idx - r*80;
      g1[r][k2] = raw[r][k2]*invX[r] + raw[r][80+k2]*invG[r]
                + ws[WSL+k2]*lscA[r] + ws[WSC1+k2];
    }
  }
  __syncthreads();

  if (tid < 160) {                              // cell 1
    const int r = tid / 20, j = tid - r*20;
    const float gi = g1[r][j], gf = g1[r][20+j], gc = g1[r][40+j], go = g1[r][60+j];
    const float c1 = fsig(gf)*c10[j] + fsig(gi)*ftanh(gc);
    h1s[r][j] = fsig(go)*ftanh(c1);
  }
  __syncthreads();

  for (int q = 0; q < 3; ++q) {                 // gates 2
    const int idx = q*256 + tid;
    if (idx < 640) {
      const int r = idx / 80, k2 = idx - r*80;
      float s = ws[WSC2+k2];
      #pragma unroll
      for (int j = 0; j < 20; ++j) s += wih2s[k2*20+j]*h1s[r][j];
      g1[r][k2] = s;
    }
  }
  __syncthreads();

  if (tid < 160) {                              // cell 2
    const int r = tid / 20, j = tid - r*20;
    const float gi = g1[r][j], gf = g1[r][20+j], gc = g1[r][40+j], go = g1[r][60+j];
    const float c2v = fsig(gf)*c20[j] + fsig(gi)*ftanh(gc);
    h2s[r][j] = fsig(go)*ftanh(c2v);
  }
  __syncthreads();

  const float pf = ws[WSPF];                    // output GEMV + tanh + scale
  #pragma unroll
  for (int q = 0; q < 8; ++q) {
    const int d = q*256 + tid;
    const float4* wr = (const float4*)(W_out + (size_t)d*20);
    const float4 w0 = wr[0], w1 = wr[1], w2 = wr[2], w3 = wr[3], w4 = wr[4];
    const float bo = b_out[d];
    #pragma unroll
    for (int r = 0; r < 8; ++r) {
      const float4* hp = (const float4*)&h2s[r][0];
      const float4 h0 = hp[0], h1v = hp[1], h2v = hp[2], h3v = hp[3], h4v = hp[4];
      float v = bo;
      v += w0.x*h0.x  + w0.y*h0.y  + w0.z*h0.z  + w0.w*h0.w;
      v += w1.x*h1v.x + w1.y*h1v.y + w1.z*h1v.z + w1.w*h1v.w;
      v += w2.x*h2v.x + w2.y*h2v.y + w2.z*h2v.z + w2.w*h2v.w;
      v += w3.x*h3v.x + w3.y*h3v.y + w3.z*h3v.z + w3.w*h3v.w;
      v += w4.x*h4v.x + w4.y*h4v.y + w4.z*h4v.z + w4.w*h4v.w;
      out[(size_t)(r0+r)*2048 + d] = pf * axv[r] * ftanh(v);
    }
  }
}

extern "C" void kernel_launch(void* const* d_in, const int* in_sizes, int n_in,
                              void* d_out, int out_size, void* d_ws, size_t ws_size,
                              hipStream_t stream)
{
  const float* x      = (const float*)d_in[0];
  const float* loss   = (const float*)d_in[1];
  const float* grad   = (const float*)d_in[2];
  const float* W_ih1  = (const float*)d_in[3];
  const float* b_ih1  = (const float*)d_in[4];
  const float* W_hh1  = (const float*)d_in[5];
  const float* b_hh1  = (const float*)d_in[6];
  const float* W_ih2  = (const float*)d_in[7];
  const float* b_ih2  = (const float*)d_in[8];
  const float* W_hh2  = (const float*)d_in[9];
  const float* b_hh2  = (const float*)d_in[10];
  const float* W_out  = (const float*)d_in[11];
  const float* b_out  = (const float*)d_in[12];
  const float* h1_0   = (const float*)d_in[13];
  const float* c1_0   = (const float*)d_in[14];
  const float* h2_0   = (const float*)d_in[15];
  const float* c2_0   = (const float*)d_in[16];
  const float* alpha  = (const float*)d_in[17];
  const int*   t      = (const int*)d_in[18];
  float* ws  = (float*)d_ws;
  float* out = (float*)d_out;

  // zero the norm area (atomicMax target); PART is fully overwritten, no init.
  hipMemsetAsync(ws + NORMX, 0, 2*4096*sizeof(float), stream);

  hipLaunchKernelGGL(prep_kernel, dim3(160), dim3(256), 0, stream,
                     W_ih1, b_ih1, W_hh1, b_hh1, b_ih2, W_hh2, b_hh2,
                     h1_0, h2_0, alpha, t, ws);

  const size_t base = (size_t)PART * sizeof(float);
  const size_t per_slice = (size_t)4096 * 160 * sizeof(float);
  if (ws_size >= base + 8*per_slice) {
    hipLaunchKernelGGL(gemm_kernel<8>, dim3(64*8), dim3(512), 0, stream, x, grad, ws, ws);
    hipLaunchKernelGGL(tail_kernel<8>, dim3(512), dim3(256), 0, stream,
                       loss, W_ih2, W_out, b_out, c1_0, c2_0, ws, out);
  } else if (ws_size >= base + 4*per_slice) {
    hipLaunchKernelGGL(gemm_kernel<4>, dim3(64*4), dim3(512), 0, stream, x, grad, ws, ws);
    hipLaunchKernelGGL(tail_kernel<4>, dim3(512), dim3(256), 0, stream,
                       loss, W_ih2, W_out, b_out, c1_0, c2_0, ws, out);
  } else if (ws_size >= base + 2*per_slice) {
    hipLaunchKernelGGL(gemm_kernel<2>, dim3(64*2), dim3(512), 0, stream, x, grad, ws, ws);
    hipLaunchKernelGGL(tail_kernel<2>, dim3(512), dim3(256), 0, stream,
                       loss, W_ih2, W_out, b_out, c1_0, c2_0, ws, out);
  } else {
    hipLaunchKernelGGL(gemm_kernel<1>, dim3(64), dim3(512), 0, stream, x, grad, ws, ws);
    hipLaunchKernelGGL(tail_kernel<1>, dim3(512), dim3(256), 0, stream,
                       loss, W_ih2, W_out, b_out, c1_0, c2_0, ws, out);
  }
}

// Round 8
// 61.167 us; speedup vs baseline: 5.6806x; 3.4079x over previous
//
#include <hip/hip_runtime.h>

typedef __attribute__((ext_vector_type(8))) short short8v;
typedef __attribute__((ext_vector_type(4))) float f32x4;

// ws layout (float offsets)
//  [0 .. 163839]   bf16 panel [gate(160)][k(2048)]  (ushort)
#define WSL   163840           // loss column (80)
#define WSC1  (WSL+80)         // folded gate-1 constants (80)
#define WSC2  (WSC1+80)        // folded gate-2 constants (80)
#define WSPF  (WSC2+80)        // poly factor
#define NORMX 164096           // 4096 row maxes of |x|   (f32 via uint atomicMax)
#define NORMG (NORMX+4096)     // 4096 row maxes of |grad|
#define H2S   172288           // h2 state [4096][20] f32
#define PART  254208           // f32 partials [NS][4096][160]

__device__ __forceinline__ float fsig(float x){ return 1.0f/(1.0f + __expf(-x)); }
__device__ __forceinline__ float ftanh(float x){ float e = __expf(2.0f*x); return 1.0f - 2.0f/(e+1.0f); }
__device__ __forceinline__ unsigned short f2bf_rne(float f){
  unsigned u = __float_as_uint(f);
  u += 0x7fffu + ((u >> 16) & 1u);
  return (unsigned short)(u >> 16);
}
__device__ __forceinline__ unsigned pack2bf(float lo, float hi){
  unsigned a = __float_as_uint(lo) + 0x8000u;
  unsigned b = __float_as_uint(hi) + 0x8000u;
  return (a >> 16) | (b & 0xFFFF0000u);
}

__global__ __launch_bounds__(256,1) void prep_kernel(
    const float* __restrict__ W_ih1, const float* __restrict__ b_ih1,
    const float* __restrict__ W_hh1, const float* __restrict__ b_hh1,
    const float* __restrict__ b_ih2, const float* __restrict__ W_hh2,
    const float* __restrict__ b_hh2, const float* __restrict__ h1_0,
    const float* __restrict__ h2_0, const float* __restrict__ alpha_raw,
    const int* __restrict__ t, float* __restrict__ ws)
{
  const int g = blockIdx.x;            // 160 gates: 0..79 x-part, 80..159 grad-part
  const int wr = (g < 80) ? g : g - 80;
  const float* src = W_ih1 + (size_t)wr*4097 + ((g < 80) ? 0 : 2049);
  unsigned short* dst = (unsigned short*)ws + (size_t)g*2048;
  for (int k = threadIdx.x; k < 2048; k += 256) dst[k] = f2bf_rne(src[k]);
  if (g == 0) {
    const int tix = threadIdx.x;
    if (tix < 80) {
      float s = b_ih1[tix] + b_hh1[tix];
      for (int j = 0; j < 20; ++j) s += W_hh1[tix*20+j]*h1_0[j];
      ws[WSC1+tix] = s;
    } else if (tix < 160) {
      const int kk = tix - 80;
      float s = b_ih2[kk] + b_hh2[kk];
      for (int j = 0; j < 20; ++j) s += W_hh2[kk*20+j]*h2_0[j];
      ws[WSC2+kk] = s;
    } else if (tix < 240) {
      const int kk = tix - 160;
      ws[WSL+kk] = W_ih1[(size_t)kk*4097 + 2048];   // loss column
    } else if (tix == 240) {
      const float tv = (float)(*t);
      float pf = 0.f, term = 1.f;
      for (int j = 0; j < 3; ++j) {
        float a = alpha_raw[j];
        float sp = (a > 20.f) ? a : log1pf(__expf(a));
        pf += sp*term; term *= tv;                   // t^0 == 1 even at t=0
      }
      pf *= powf(0.99f, tv);
      ws[WSPF] = pf;
    }
  }
}

// GEMM: grid = 64 rowblocks x NS kslices, 512 thr = 8 waves (4 m-tiles x 2 parts).
// B chunk (160 gates x 128 k bf16 = 40KB) staged in LDS, XOR-swizzled.
template<int NS>
__global__ __launch_bounds__(512,2) void gemm_kernel(
    const float* __restrict__ x, const float* __restrict__ grad,
    const float* ws, float* wsw)
{
  constexpr int KS  = 2048 / NS;       // K per slice (per part)
  constexpr int NCH = KS / 128;        // 128-col chunks per slice
  __shared__ unsigned short bs[160*128];   // 40 KB

  const int tid = threadIdx.x;
  const int w = tid >> 6, lane = tid & 63;
  const int mt = w >> 1, gh = w & 1;   // m-tile 0..3, part: 0=x 1=grad
  const int m = lane & 15, kg = lane >> 4;
  const int rb  = blockIdx.x / NS, ksl = blockIdx.x % NS;
  const int r0  = rb*64;
  const int kbase = ksl*KS;
  const unsigned short* panel = (const unsigned short*)ws;
  const float* Ap = (gh ? grad : x) + (size_t)(r0 + mt*16 + m)*2048;
  const int xk = (m & 7) << 4;         // per-lane swizzle constant

  f32x4 acc[5];
  #pragma unroll
  for (int t = 0; t < 5; ++t) acc[t] = (f32x4){0.f,0.f,0.f,0.f};
  float vm = 0.f;

  #pragma unroll 1
  for (int c = 0; c < NCH; ++c) {
    const int kb = kbase + c*128;
    // ---- stage B chunk: 160 gates x 16 chunks of 16B, swizzled ----
    #pragma unroll
    for (int q = 0; q < 5; ++q) {
      const int j = q*512 + tid;       // 0..2559
      const int g = j >> 4, ku = j & 15;
      const uint4 v = *(const uint4*)(panel + (size_t)g*2048 + kb + ku*8);
      *(uint4*)((char*)bs + g*256 + ((ku*16) ^ ((g & 7) << 4))) = v;
    }
    __syncthreads();
    // ---- 4 k-steps x 5 MFMA ----
    #pragma unroll
    for (int ks = 0; ks < 4; ++ks) {
      const float* ap = Ap + kb + ks*32 + kg*8;
      const f32x4 a0 = *(const f32x4*)ap;
      const f32x4 a1 = *(const f32x4*)(ap + 4);
      vm = fmaxf(vm, fmaxf(fmaxf(fabsf(a0.x),fabsf(a0.y)), fmaxf(fabsf(a0.z),fabsf(a0.w))));
      vm = fmaxf(vm, fmaxf(fmaxf(fabsf(a1.x),fabsf(a1.y)), fmaxf(fabsf(a1.z),fabsf(a1.w))));
      union { unsigned u[4]; short8v v; } A_;
      A_.u[0] = pack2bf(a0.x, a0.y);
      A_.u[1] = pack2bf(a0.z, a0.w);
      A_.u[2] = pack2bf(a1.x, a1.y);
      A_.u[3] = pack2bf(a1.z, a1.w);
      const short8v af = A_.v;
      const int kof = (ks*64 + kg*16) ^ xk;
      #pragma unroll
      for (int t = 0; t < 5; ++t) {
        const int lg = gh*80 + t*16 + m;
        const short8v bf = *(const short8v*)((char*)bs + lg*256 + kof);
        acc[t] = __builtin_amdgcn_mfma_f32_16x16x32_bf16(af, bf, acc[t], 0, 0, 0);
      }
    }
    __syncthreads();
  }

  // ---- row inf-norm: reduce over kg lanes, one global atomicMax per row ----
  vm = fmaxf(vm, __shfl_xor(vm, 16));
  vm = fmaxf(vm, __shfl_xor(vm, 32));
  if (lane < 16)
    atomicMax((unsigned*)wsw + (gh ? NORMG : NORMX) + r0 + mt*16 + m,
              __float_as_uint(vm));

  // ---- per-slice partials (exclusive ownership, no atomics) ----
  float* pp = wsw + PART + ((size_t)ksl*4096 + r0 + mt*16 + kg*4)*160 + gh*80 + m;
  #pragma unroll
  for (int t = 0; t < 5; ++t)
    #pragma unroll
    for (int r = 0; r < 4; ++r)
      pp[(size_t)r*160 + t*16] = acc[t][r];
}

// tail: 512 blocks x 256 thr; 8 rows: reduce NS slices -> gates -> cells -> h2 to ws
template<int NS>
__global__ __launch_bounds__(256,4) void tail_kernel(
    const float* __restrict__ loss, const float* __restrict__ W_ih2,
    const float* __restrict__ c1_0, const float* __restrict__ c2_0,
    const float* ws, float* __restrict__ wsw)
{
  __shared__ float raw[8][160];
  __shared__ float g1[8][80];
  __shared__ float wih2s[1600];
  __shared__ float h1s[8][20], h2s[8][20];
  __shared__ float c10[20], c20[20];
  __shared__ float invX[8], invG[8], lscA[8];

  const int tid = threadIdx.x;
  const int r0  = blockIdx.x * 8;

  for (int i = tid; i < 1600; i += 256) wih2s[i] = W_ih2[i];
  if (tid < 20) { c10[tid] = c1_0[tid]; c20[tid] = c2_0[tid]; }

  #pragma unroll
  for (int q = 0; q < 5; ++q) {                 // reduce partials (8x160)
    const int idx = q*256 + tid;
    const int r = idx / 160, gt = idx - r*160;
    float s = 0.f;
    #pragma unroll
    for (int sl = 0; sl < NS; ++sl)
      s += ws[PART + ((size_t)sl*4096 + r0 + r)*160 + gt];
    raw[r][gt] = s;
  }
  if (tid < 8) {
    float ax = ws[NORMX + r0 + tid]; ax = (ax > 0.f) ? ax : 1.0f;
    invX[tid] = 1.0f/ax;
    float ag = ws[NORMG + r0 + tid]; ag = (ag > 0.f) ? ag : 1.0f;
    invG[tid] = 1.0f/ag;
    float l  = loss[r0 + tid];
    float al = fabsf(l); al = (al > 0.f) ? al : 1.0f;
    lscA[tid] = l / al;
  }
  __syncthreads();

  for (int q = 0; q < 3; ++q) {                 // gates 1 (8x80)
    const int idx = q*256 + tid;
    if (idx < 640) {
      const int r = idx / 80, k2 = idx - r*80;
      g1[r][k2] = raw[r][k2]*invX[r] + raw[r][80+k2]*invG[r]
                + ws[WSL+k2]*lscA[r] + ws[WSC1+k2];
    }
  }
  __syncthreads();

  if (tid < 160) {                              // cell 1
    const int r = tid / 20, j = tid - r*20;
    const float gi = g1[r][j], gf = g1[r][20+j], gc = g1[r][40+j], go = g1[r][60+j];
    const float c1 = fsig(gf)*c10[j] + fsig(gi)*ftanh(gc);
    h1s[r][j] = fsig(go)*ftanh(c1);
  }
  __syncthreads();

  for (int q = 0; q < 3; ++q) {                 // gates 2
    const int idx = q*256 + tid;
    if (idx < 640) {
      const int r = idx / 80, k2 = idx - r*80;
      float s = ws[WSC2+k2];
      #pragma unroll
      for (int j = 0; j < 20; ++j) s += wih2s[k2*20+j]*h1s[r][j];
      g1[r][k2] = s;
    }
  }
  __syncthreads();

  if (tid < 160) {                              // cell 2 -> h2 to ws
    const int r = tid / 20, j = tid - r*20;
    const float gi = g1[r][j], gf = g1[r][20+j], gc = g1[r][40+j], go = g1[r][60+j];
    const float c2v = fsig(gf)*c20[j] + fsig(gi)*ftanh(gc);
    wsw[H2S + (size_t)(r0 + r)*20 + j] = fsig(go)*ftanh(c2v);
  }
}

// output GEMM: grid 64 rowblocks x 8 dblocks (dblk = blockIdx&7 -> per-XCD W_out
// slice, L2-resident 20KB). Thread owns one d-column (W_out row in regs), loops
// 64 rows from LDS-staged h2. Pure write-bound.
__global__ __launch_bounds__(256,4) void outgemm_kernel(
    const float* __restrict__ W_out, const float* __restrict__ b_out,
    const float* ws, float* __restrict__ out)
{
  __shared__ float h2s[64][20];
  __shared__ float axs[64];
  const int tid = threadIdx.x;
  const int db = blockIdx.x & 7, rbk = blockIdx.x >> 3;
  const int row0 = rbk * 64;
  const int d = db*256 + tid;

  for (int i = tid; i < 1280; i += 256) (&h2s[0][0])[i] = ws[H2S + (size_t)row0*20 + i];
  if (tid < 64) {
    float ax = ws[NORMX + row0 + tid];
    axs[tid] = (ax > 0.f) ? ax : 1.0f;
  }
  __syncthreads();

  const float4* wr = (const float4*)(W_out + (size_t)d*20);
  const float4 w0 = wr[0], w1 = wr[1], w2 = wr[2], w3 = wr[3], w4 = wr[4];
  const float bo = b_out[d];
  const float pf = ws[WSPF];

  #pragma unroll 4
  for (int r = 0; r < 64; ++r) {
    const float4* hp = (const float4*)&h2s[r][0];
    const float4 h0 = hp[0], h1v = hp[1], h2v = hp[2], h3v = hp[3], h4v = hp[4];
    float v = bo;
    v += w0.x*h0.x  + w0.y*h0.y  + w0.z*h0.z  + w0.w*h0.w;
    v += w1.x*h1v.x + w1.y*h1v.y + w1.z*h1v.z + w1.w*h1v.w;
    v += w2.x*h2v.x + w2.y*h2v.y + w2.z*h2v.z + w2.w*h2v.w;
    v += w3.x*h3v.x + w3.y*h3v.y + w3.z*h3v.z + w3.w*h3v.w;
    v += w4.x*h4v.x + w4.y*h4v.y + w4.z*h4v.z + w4.w*h4v.w;
    out[(size_t)(row0+r)*2048 + d] = pf * axs[r] * ftanh(v);
  }
}

extern "C" void kernel_launch(void* const* d_in, const int* in_sizes, int n_in,
                              void* d_out, int out_size, void* d_ws, size_t ws_size,
                              hipStream_t stream)
{
  const float* x      = (const float*)d_in[0];
  const float* loss   = (const float*)d_in[1];
  const float* grad   = (const float*)d_in[2];
  const float* W_ih1  = (const float*)d_in[3];
  const float* b_ih1  = (const float*)d_in[4];
  const float* W_hh1  = (const float*)d_in[5];
  const float* b_hh1  = (const float*)d_in[6];
  const float* W_ih2  = (const float*)d_in[7];
  const float* b_ih2  = (const float*)d_in[8];
  const float* W_hh2  = (const float*)d_in[9];
  const float* b_hh2  = (const float*)d_in[10];
  const float* W_out  = (const float*)d_in[11];
  const float* b_out  = (const float*)d_in[12];
  const float* h1_0   = (const float*)d_in[13];
  const float* c1_0   = (const float*)d_in[14];
  const float* h2_0   = (const float*)d_in[15];
  const float* c2_0   = (const float*)d_in[16];
  const float* alpha  = (const float*)d_in[17];
  const int*   t      = (const int*)d_in[18];
  float* ws  = (float*)d_ws;
  float* out = (float*)d_out;

  // zero the norm area (atomicMax target); PART/H2S fully overwritten, no init.
  hipMemsetAsync(ws + NORMX, 0, 2*4096*sizeof(float), stream);

  hipLaunchKernelGGL(prep_kernel, dim3(160), dim3(256), 0, stream,
                     W_ih1, b_ih1, W_hh1, b_hh1, b_ih2, W_hh2, b_hh2,
                     h1_0, h2_0, alpha, t, ws);

  const size_t base = (size_t)PART * sizeof(float);
  const size_t per_slice = (size_t)4096 * 160 * sizeof(float);
  if (ws_size >= base + 8*per_slice) {
    hipLaunchKernelGGL(gemm_kernel<8>, dim3(64*8), dim3(512), 0, stream, x, grad, ws, ws);
    hipLaunchKernelGGL(tail_kernel<8>, dim3(512), dim3(256), 0, stream,
                       loss, W_ih2, c1_0, c2_0, ws, ws);
  } else if (ws_size >= base + 4*per_slice) {
    hipLaunchKernelGGL(gemm_kernel<4>, dim3(64*4), dim3(512), 0, stream, x, grad, ws, ws);
    hipLaunchKernelGGL(tail_kernel<4>, dim3(512), dim3(256), 0, stream,
                       loss, W_ih2, c1_0, c2_0, ws, ws);
  } else if (ws_size >= base + 2*per_slice) {
    hipLaunchKernelGGL(gemm_kernel<2>, dim3(64*2), dim3(512), 0, stream, x, grad, ws, ws);
    hipLaunchKernelGGL(tail_kernel<2>, dim3(512), dim3(256), 0, stream,
                       loss, W_ih2, c1_0, c2_0, ws, ws);
  } else {
    hipLaunchKernelGGL(gemm_kernel<1>, dim3(64), dim3(512), 0, stream, x, grad, ws, ws);
    hipLaunchKernelGGL(tail_kernel<1>, dim3(512), dim3(256), 0, stream,
                       loss, W_ih2, c1_0, c2_0, ws, ws);
  }
  hipLaunchKernelGGL(outgemm_kernel, dim3(512), dim3(256), 0, stream,
                     W_out, b_out, ws, out);
}

// Round 9
// 58.317 us; speedup vs baseline: 5.9582x; 1.0489x over previous
//
#include <hip/hip_runtime.h>

typedef __attribute__((ext_vector_type(8))) short short8v;
typedef __attribute__((ext_vector_type(4))) float f32x4;

// ws layout (float offsets)
//  [0 .. 163839]   bf16 panel [gate(160)][k(2048)]  (ushort)
#define WSL   163840           // loss column (80)
#define WSC1  (WSL+80)         // folded gate-1 constants (80)
#define WSC2  (WSC1+80)        // folded gate-2 constants (80)
#define WSPF  (WSC2+80)        // poly factor
#define NORMX 164096           // 4096 row maxes of |x|   (f32 via uint atomicMax)
#define NORMG (NORMX+4096)     // 4096 row maxes of |grad|
#define H2S   172288           // h2 state [4096][20] f32
#define PART  254208           // f32 partials [NS][4096][160]

__device__ __forceinline__ float fsig(float x){ return 1.0f/(1.0f + __expf(-x)); }
__device__ __forceinline__ float ftanh(float x){ float e = __expf(2.0f*x); return 1.0f - 2.0f/(e+1.0f); }
__device__ __forceinline__ unsigned short f2bf_rne(float f){
  unsigned u = __float_as_uint(f);
  u += 0x7fffu + ((u >> 16) & 1u);
  return (unsigned short)(u >> 16);
}
__device__ __forceinline__ unsigned pack2bf(float lo, float hi){
  unsigned a = __float_as_uint(lo) + 0x8000u;
  unsigned b = __float_as_uint(hi) + 0x8000u;
  return (a >> 16) | (b & 0xFFFF0000u);
}

// prep: blocks 0..159 repack W_ih1 -> bf16 panel; blocks 160..191 zero norms.
__global__ __launch_bounds__(256,1) void prep_kernel(
    const float* __restrict__ W_ih1, const float* __restrict__ b_ih1,
    const float* __restrict__ W_hh1, const float* __restrict__ b_hh1,
    const float* __restrict__ b_ih2, const float* __restrict__ W_hh2,
    const float* __restrict__ b_hh2, const float* __restrict__ h1_0,
    const float* __restrict__ h2_0, const float* __restrict__ alpha_raw,
    const int* __restrict__ t, float* __restrict__ ws)
{
  const int g = blockIdx.x;
  if (g >= 160) {                      // zero the 2*4096 norm slots
    ws[NORMX + (g - 160)*256 + threadIdx.x] = 0.f;
    return;
  }
  const int wr = (g < 80) ? g : g - 80;
  const float* src = W_ih1 + (size_t)wr*4097 + ((g < 80) ? 0 : 2049);
  unsigned short* dst = (unsigned short*)ws + (size_t)g*2048;
  for (int k = threadIdx.x; k < 2048; k += 256) dst[k] = f2bf_rne(src[k]);
  if (g == 0) {
    const int tix = threadIdx.x;
    if (tix < 80) {
      float s = b_ih1[tix] + b_hh1[tix];
      for (int j = 0; j < 20; ++j) s += W_hh1[tix*20+j]*h1_0[j];
      ws[WSC1+tix] = s;
    } else if (tix < 160) {
      const int kk = tix - 80;
      float s = b_ih2[kk] + b_hh2[kk];
      for (int j = 0; j < 20; ++j) s += W_hh2[kk*20+j]*h2_0[j];
      ws[WSC2+kk] = s;
    } else if (tix < 240) {
      const int kk = tix - 160;
      ws[WSL+kk] = W_ih1[(size_t)kk*4097 + 2048];   // loss column
    } else if (tix == 240) {
      const float tv = (float)(*t);
      float pf = 0.f, term = 1.f;
      for (int j = 0; j < 3; ++j) {
        float a = alpha_raw[j];
        float sp = (a > 20.f) ? a : log1pf(__expf(a));
        pf += sp*term; term *= tv;                   // t^0 == 1 even at t=0
      }
      pf *= powf(0.99f, tv);
      ws[WSPF] = pf;
    }
  }
}

// GEMM: grid = 64 rowblocks x NS kslices, 512 thr = 8 waves (4 m-tiles x 2 parts).
// B chunk (160 gates x 128 k bf16 = 40KB) staged in LDS, XOR-swizzled.
// A loads + partial stores non-temporal (protect B panel in L2).
template<int NS>
__global__ __launch_bounds__(512,2) void gemm_kernel(
    const float* __restrict__ x, const float* __restrict__ grad,
    const float* ws, float* wsw)
{
  constexpr int KS  = 2048 / NS;       // K per slice (per part)
  constexpr int NCH = KS / 128;        // 128-col chunks per slice
  __shared__ unsigned short bs[160*128];   // 40 KB

  const int tid = threadIdx.x;
  const int w = tid >> 6, lane = tid & 63;
  const int mt = w >> 1, gh = w & 1;   // m-tile 0..3, part: 0=x 1=grad
  const int m = lane & 15, kg = lane >> 4;
  const int rb  = blockIdx.x / NS, ksl = blockIdx.x % NS;
  const int r0  = rb*64;
  const int kbase = ksl*KS;
  const unsigned short* panel = (const unsigned short*)ws;
  const float* Ap = (gh ? grad : x) + (size_t)(r0 + mt*16 + m)*2048;
  const int xk = (m & 7) << 4;         // per-lane swizzle constant

  f32x4 acc[5];
  #pragma unroll
  for (int t = 0; t < 5; ++t) acc[t] = (f32x4){0.f,0.f,0.f,0.f};
  float vm = 0.f;

  #pragma unroll 1
  for (int c = 0; c < NCH; ++c) {
    const int kb = kbase + c*128;
    // ---- stage B chunk: 160 gates x 16 chunks of 16B, swizzled ----
    #pragma unroll
    for (int q = 0; q < 5; ++q) {
      const int j = q*512 + tid;       // 0..2559
      const int g = j >> 4, ku = j & 15;
      const uint4 v = *(const uint4*)(panel + (size_t)g*2048 + kb + ku*8);
      *(uint4*)((char*)bs + g*256 + ((ku*16) ^ ((g & 7) << 4))) = v;
    }
    __syncthreads();
    // ---- 4 k-steps x 5 MFMA ----
    #pragma unroll
    for (int ks = 0; ks < 4; ++ks) {
      const float* ap = Ap + kb + ks*32 + kg*8;
      const f32x4 a0 = __builtin_nontemporal_load((const f32x4*)ap);
      const f32x4 a1 = __builtin_nontemporal_load((const f32x4*)(ap + 4));
      vm = fmaxf(vm, fmaxf(fmaxf(fabsf(a0.x),fabsf(a0.y)), fmaxf(fabsf(a0.z),fabsf(a0.w))));
      vm = fmaxf(vm, fmaxf(fmaxf(fabsf(a1.x),fabsf(a1.y)), fmaxf(fabsf(a1.z),fabsf(a1.w))));
      union { unsigned u[4]; short8v v; } A_;
      A_.u[0] = pack2bf(a0.x, a0.y);
      A_.u[1] = pack2bf(a0.z, a0.w);
      A_.u[2] = pack2bf(a1.x, a1.y);
      A_.u[3] = pack2bf(a1.z, a1.w);
      const short8v af = A_.v;
      const int kof = (ks*64 + kg*16) ^ xk;
      #pragma unroll
      for (int t = 0; t < 5; ++t) {
        const int lg = gh*80 + t*16 + m;
        const short8v bf = *(const short8v*)((char*)bs + lg*256 + kof);
        acc[t] = __builtin_amdgcn_mfma_f32_16x16x32_bf16(af, bf, acc[t], 0, 0, 0);
      }
    }
    __syncthreads();
  }

  // ---- row inf-norm: reduce over kg lanes, one global atomicMax per row ----
  vm = fmaxf(vm, __shfl_xor(vm, 16));
  vm = fmaxf(vm, __shfl_xor(vm, 32));
  if (lane < 16)
    atomicMax((unsigned*)wsw + (gh ? NORMG : NORMX) + r0 + mt*16 + m,
              __float_as_uint(vm));

  // ---- per-slice partials (exclusive ownership, no atomics), NT stores ----
  float* pp = wsw + PART + ((size_t)ksl*4096 + r0 + mt*16 + kg*4)*160 + gh*80 + m;
  #pragma unroll
  for (int t = 0; t < 5; ++t)
    #pragma unroll
    for (int r = 0; r < 4; ++r)
      __builtin_nontemporal_store(acc[t][r], pp + (size_t)r*160 + t*16);
}

// tail: 512 blocks x 256 thr; 8 rows: reduce NS slices -> gates -> cells -> h2 to ws
template<int NS>
__global__ __launch_bounds__(256,4) void tail_kernel(
    const float* __restrict__ loss, const float* __restrict__ W_ih2,
    const float* __restrict__ c1_0, const float* __restrict__ c2_0,
    const float* ws, float* __restrict__ wsw)
{
  __shared__ float raw[8][160];
  __shared__ float g1[8][80];
  __shared__ float wih2s[1600];
  __shared__ float h1s[8][20];
  __shared__ float c10[20], c20[20];
  __shared__ float invX[8], invG[8], lscA[8];

  const int tid = threadIdx.x;
  const int r0  = blockIdx.x * 8;

  for (int i = tid; i < 1600; i += 256) wih2s[i] = W_ih2[i];
  if (tid < 20) { c10[tid] = c1_0[tid]; c20[tid] = c2_0[tid]; }

  // reduce partials: 8 rows x 40 float4, NT loads
  for (int idx = tid; idx < 320; idx += 256) {
    const int r = idx / 40, c4 = idx - r*40;
    f32x4 s = (f32x4){0.f,0.f,0.f,0.f};
    #pragma unroll
    for (int sl = 0; sl < NS; ++sl) {
      const f32x4 v = __builtin_nontemporal_load(
          (const f32x4*)(ws + PART + ((size_t)sl*4096 + r0 + r)*160 + c4*4));
      s.x += v.x; s.y += v.y; s.z += v.z; s.w += v.w;
    }
    *(f32x4*)&raw[r][c4*4] = s;
  }
  if (tid < 8) {
    float ax = ws[NORMX + r0 + tid]; ax = (ax > 0.f) ? ax : 1.0f;
    invX[tid] = 1.0f/ax;
    float ag = ws[NORMG + r0 + tid]; ag = (ag > 0.f) ? ag : 1.0f;
    invG[tid] = 1.0f/ag;
    float l  = loss[r0 + tid];
    float al = fabsf(l); al = (al > 0.f) ? al : 1.0f;
    lscA[tid] = l / al;
  }
  __syncthreads();

  for (int q = 0; q < 3; ++q) {                 // gates 1 (8x80)
    const int idx = q*256 + tid;
    if (idx < 640) {
      const int r = idx / 80, k2 = idx - r*80;
      g1[r][k2] = raw[r][k2]*invX[r] + raw[r][80+k2]*invG[r]
                + ws[WSL+k2]*lscA[r] + ws[WSC1+k2];
    }
  }
  __syncthreads();

  if (tid < 160) {                              // cell 1
    const int r = tid / 20, j = tid - r*20;
    const float gi = g1[r][j], gf = g1[r][20+j], gc = g1[r][40+j], go = g1[r][60+j];
    const float c1 = fsig(gf)*c10[j] + fsig(gi)*ftanh(gc);
    h1s[r][j] = fsig(go)*ftanh(c1);
  }
  __syncthreads();

  for (int q = 0; q < 3; ++q) {                 // gates 2
    const int idx = q*256 + tid;
    if (idx < 640) {
      const int r = idx / 80, k2 = idx - r*80;
      float s = ws[WSC2+k2];
      #pragma unroll
      for (int j = 0; j < 20; ++j) s += wih2s[k2*20+j]*h1s[r][j];
      g1[r][k2] = s;
    }
  }
  __syncthreads();

  if (tid < 160) {                              // cell 2 -> h2 to ws
    const int r = tid / 20, j = tid - r*20;
    const float gi = g1[r][j], gf = g1[r][20+j], gc = g1[r][40+j], go = g1[r][60+j];
    const float c2v = fsig(gf)*c20[j] + fsig(gi)*ftanh(gc);
    wsw[H2S + (size_t)(r0 + r)*20 + j] = fsig(go)*ftanh(c2v);
  }
}

// output GEMM: grid 64 rowblocks x 8 dblocks (dblk -> per-XCD W_out slice,
// L2-resident 20KB). Thread owns one d-column, loops 64 rows from LDS h2.
__global__ __launch_bounds__(256,4) void outgemm_kernel(
    const float* __restrict__ W_out, const float* __restrict__ b_out,
    const float* ws, float* __restrict__ out)
{
  __shared__ float h2s[64][20];
  __shared__ float axs[64];
  const int tid = threadIdx.x;
  const int db = blockIdx.x & 7, rbk = blockIdx.x >> 3;
  const int row0 = rbk * 64;
  const int d = db*256 + tid;

  for (int i = tid; i < 1280; i += 256) (&h2s[0][0])[i] = ws[H2S + (size_t)row0*20 + i];
  if (tid < 64) {
    float ax = ws[NORMX + row0 + tid];
    axs[tid] = (ax > 0.f) ? ax : 1.0f;
  }
  __syncthreads();

  const float4* wr = (const float4*)(W_out + (size_t)d*20);
  const float4 w0 = wr[0], w1 = wr[1], w2 = wr[2], w3 = wr[3], w4 = wr[4];
  const float bo = b_out[d];
  const float pf = ws[WSPF];

  #pragma unroll 4
  for (int r = 0; r < 64; ++r) {
    const float4* hp = (const float4*)&h2s[r][0];
    const float4 h0 = hp[0], h1v = hp[1], h2v = hp[2], h3v = hp[3], h4v = hp[4];
    float v = bo;
    v += w0.x*h0.x  + w0.y*h0.y  + w0.z*h0.z  + w0.w*h0.w;
    v += w1.x*h1v.x + w1.y*h1v.y + w1.z*h1v.z + w1.w*h1v.w;
    v += w2.x*h2v.x + w2.y*h2v.y + w2.z*h2v.z + w2.w*h2v.w;
    v += w3.x*h3v.x + w3.y*h3v.y + w3.z*h3v.z + w3.w*h3v.w;
    v += w4.x*h4v.x + w4.y*h4v.y + w4.z*h4v.z + w4.w*h4v.w;
    __builtin_nontemporal_store(pf * axs[r] * ftanh(v),
                                &out[(size_t)(row0+r)*2048 + d]);
  }
}

extern "C" void kernel_launch(void* const* d_in, const int* in_sizes, int n_in,
                              void* d_out, int out_size, void* d_ws, size_t ws_size,
                              hipStream_t stream)
{
  const float* x      = (const float*)d_in[0];
  const float* loss   = (const float*)d_in[1];
  const float* grad   = (const float*)d_in[2];
  const float* W_ih1  = (const float*)d_in[3];
  const float* b_ih1  = (const float*)d_in[4];
  const float* W_hh1  = (const float*)d_in[5];
  const float* b_hh1  = (const float*)d_in[6];
  const float* W_ih2  = (const float*)d_in[7];
  const float* b_ih2  = (const float*)d_in[8];
  const float* W_hh2  = (const float*)d_in[9];
  const float* b_hh2  = (const float*)d_in[10];
  const float* W_out  = (const float*)d_in[11];
  const float* b_out  = (const float*)d_in[12];
  const float* h1_0   = (const float*)d_in[13];
  const float* c1_0   = (const float*)d_in[14];
  const float* h2_0   = (const float*)d_in[15];
  const float* c2_0   = (const float*)d_in[16];
  const float* alpha  = (const float*)d_in[17];
  const int*   t      = (const int*)d_in[18];
  float* ws  = (float*)d_ws;
  float* out = (float*)d_out;

  hipLaunchKernelGGL(prep_kernel, dim3(192), dim3(256), 0, stream,
                     W_ih1, b_ih1, W_hh1, b_hh1, b_ih2, W_hh2, b_hh2,
                     h1_0, h2_0, alpha, t, ws);

  const size_t base = (size_t)PART * sizeof(float);
  const size_t per_slice = (size_t)4096 * 160 * sizeof(float);
  if (ws_size >= base + 8*per_slice) {
    hipLaunchKernelGGL(gemm_kernel<8>, dim3(64*8), dim3(512), 0, stream, x, grad, ws, ws);
    hipLaunchKernelGGL(tail_kernel<8>, dim3(512), dim3(256), 0, stream,
                       loss, W_ih2, c1_0, c2_0, ws, ws);
  } else if (ws_size >= base + 4*per_slice) {
    hipLaunchKernelGGL(gemm_kernel<4>, dim3(64*4), dim3(512), 0, stream, x, grad, ws, ws);
    hipLaunchKernelGGL(tail_kernel<4>, dim3(512), dim3(256), 0, stream,
                       loss, W_ih2, c1_0, c2_0, ws, ws);
  } else if (ws_size >= base + 2*per_slice) {
    hipLaunchKernelGGL(gemm_kernel<2>, dim3(64*2), dim3(512), 0, stream, x, grad, ws, ws);
    hipLaunchKernelGGL(tail_kernel<2>, dim3(512), dim3(256), 0, stream,
                       loss, W_ih2, c1_0, c2_0, ws, ws);
  } else {
    hipLaunchKernelGGL(gemm_kernel<1>, dim3(64), dim3(512), 0, stream, x, grad, ws, ws);
    hipLaunchKernelGGL(tail_kernel<1>, dim3(512), dim3(256), 0, stream,
                       loss, W_ih2, c1_0, c2_0, ws, ws);
  }
  hipLaunchKernelGGL(outgemm_kernel, dim3(512), dim3(256), 0, stream,
                     W_out, b_out, ws, out);
}